// Round 3
// baseline (277.393 us; speedup 1.0000x reference)
//
#include <hip/hip_runtime.h>
#include <hip/hip_bf16.h>

// Problem constants (from reference setup_inputs)
#define BB 2
#define LL 4096
#define DD 256
#define KK 16
#define GG 4
#define HH 8
#define DH 64
#define PE 32
#define INNER 512          // H*DH
#define CC 21              // 1 + K + G
#define MM (BB*LL)         // 8192
#define SCALE 0.125f       // 64^-0.5

typedef unsigned short ushort4_t __attribute__((ext_vector_type(4)));
typedef unsigned short ushort8_t __attribute__((ext_vector_type(8)));

static __device__ __forceinline__ float bf2f(unsigned short u) {
    return __uint_as_float(((unsigned)u) << 16);
}
static __device__ __forceinline__ unsigned short f2bf(float f) {
    unsigned u = __float_as_uint(f);
    unsigned r = u + 0x7fffu + ((u >> 16) & 1u);   // RNE
    return (unsigned short)(r >> 16);
}

// ---------------------------------------------------------------------------
// prep_A: A[e, h*32+p] = sum_d Wq[e, h*64+d] * Wk[256+p, h*64+d]   (256x256)
// ---------------------------------------------------------------------------
__global__ __launch_bounds__(256) void prep_A(
    const float* __restrict__ Wq, const float* __restrict__ Wk,
    float* __restrict__ A)
{
    const int e = blockIdx.x;
    const int tid = threadIdx.x;
    __shared__ float qrow[INNER];
    qrow[tid]       = Wq[e * INNER + tid];
    qrow[tid + 256] = Wq[e * INNER + 256 + tid];
    __syncthreads();
    const int h = tid >> 5, p = tid & 31;
    const float* __restrict__ wr = &Wk[(size_t)(DD + p) * INNER + h * DH];
    const float* __restrict__ qh = &qrow[h * DH];
    float s = 0.f;
    #pragma unroll 8
    for (int d = 0; d < DH; ++d) s += wr[d] * qh[d];
    A[e * 256 + tid] = s;
}

// ---------------------------------------------------------------------------
// prep_M2: M2[h*32+p, n] = sum_d Wv[256+p, h*64+d] * Wo[h*64+d, n]  (256x256)
// ---------------------------------------------------------------------------
__global__ __launch_bounds__(256) void prep_M2(
    const float* __restrict__ Wv, const float* __restrict__ Wo,
    float* __restrict__ M2)
{
    const int hp = blockIdx.x;
    const int h = hp >> 5, p = hp & 31;
    const int tid = threadIdx.x;
    __shared__ float vrow[DH];
    if (tid < DH) vrow[tid] = Wv[(size_t)(DD + p) * INNER + h * DH + tid];
    __syncthreads();
    float s = 0.f;
    #pragma unroll 8
    for (int d = 0; d < DH; ++d) s += vrow[d] * Wo[(size_t)(h * DH + d) * DD + tid];
    M2[hp * 256 + tid] = s;
}

// ---------------------------------------------------------------------------
// K1: fused GEMM.  [Q | Kf | Vf | T] = spatial[M,256] @ [Wq | Wk_f | Wv_f | A]
// N = 1792; Q,Kf stored fp32, Vf,T stored bf16.
// ---------------------------------------------------------------------------
__global__ __launch_bounds__(256) void gemm_qkvt(
    const float* __restrict__ spatial,
    const float* __restrict__ Wq, const float* __restrict__ Wk,
    const float* __restrict__ Wv, const float* __restrict__ A,
    float* __restrict__ Qb, float* __restrict__ Kf,
    unsigned short* __restrict__ Vf, unsigned short* __restrict__ Tt)
{
    const int bm = blockIdx.x;
    const int bn = blockIdx.y;          // 0..27
    const int nbase = bn * 64;
    const int seg  = nbase >> 9;        // 0:Q 1:K 2:V 3:T
    const int col0 = nbase & 511;
    const float* __restrict__ W = (seg == 0) ? Wq : (seg == 1) ? Wk
                                 : (seg == 2) ? Wv : A;
    const int ldw = (seg == 3) ? 256 : INNER;
    const int ldo = (seg == 3) ? 256 : INNER;

    __shared__ float As[16][64 + 1];
    __shared__ float Bs[16][64];

    const int tid = threadIdx.x;
    const int tx = tid & 15;
    const int ty = tid >> 4;
    const int m0 = bm * 64;

    float acc[4][4] = {};

    const int ar = tid >> 2;
    const int ac = (tid & 3) << 2;
    const int br = tid >> 4;
    const int bc = (tid & 15) << 2;

    for (int k0 = 0; k0 < DD; k0 += 16) {
        float4 av = *reinterpret_cast<const float4*>(&spatial[(m0 + ar) * DD + k0 + ac]);
        As[ac + 0][ar] = av.x; As[ac + 1][ar] = av.y;
        As[ac + 2][ar] = av.z; As[ac + 3][ar] = av.w;
        float4 bv = *reinterpret_cast<const float4*>(&W[(size_t)(k0 + br) * ldw + col0 + bc]);
        *reinterpret_cast<float4*>(&Bs[br][bc]) = bv;
        __syncthreads();
        #pragma unroll
        for (int kk = 0; kk < 16; ++kk) {
            float a[4], b[4];
            #pragma unroll
            for (int i = 0; i < 4; ++i) a[i] = As[kk][ty * 4 + i];
            #pragma unroll
            for (int j = 0; j < 4; ++j) b[j] = Bs[kk][tx * 4 + j];
            #pragma unroll
            for (int i = 0; i < 4; ++i)
                #pragma unroll
                for (int j = 0; j < 4; ++j)
                    acc[i][j] += a[i] * b[j];
        }
        __syncthreads();
    }

    if (seg <= 1) {
        float* __restrict__ Out = (seg == 0) ? Qb : Kf;
        #pragma unroll
        for (int i = 0; i < 4; ++i) {
            const int m = m0 + ty * 4 + i;
            float4 v = { acc[i][0], acc[i][1], acc[i][2], acc[i][3] };
            *reinterpret_cast<float4*>(&Out[(size_t)m * ldo + col0 + tx * 4]) = v;
        }
    } else {
        unsigned short* __restrict__ Out = (seg == 2) ? Vf : Tt;
        #pragma unroll
        for (int i = 0; i < 4; ++i) {
            const int m = m0 + ty * 4 + i;
            ushort4_t v = { f2bf(acc[i][0]), f2bf(acc[i][1]),
                            f2bf(acc[i][2]), f2bf(acc[i][3]) };
            *reinterpret_cast<ushort4_t*>(&Out[(size_t)m * ldo + col0 + tx * 4]) = v;
        }
    }
}

// ---------------------------------------------------------------------------
// K1b: global-latent K/V projection.  Kg fp32, Vg bf16.
// ---------------------------------------------------------------------------
__global__ __launch_bounds__(256) void gemm_globals(
    const float* __restrict__ gl, const float* __restrict__ Wk,
    const float* __restrict__ Wv, float* __restrict__ Kg,
    unsigned short* __restrict__ Vg)
{
    const int bg  = blockIdx.x;
    const int tid = threadIdx.x;
    const int col = blockIdx.y * 128 + (tid & 127);
    const bool isv = tid >= 128;
    const float* __restrict__ W = isv ? Wv : Wk;
    const float* __restrict__ x = &gl[bg * DD];
    float s = 0.f;
    #pragma unroll 4
    for (int k = 0; k < DD; ++k) s += x[k] * W[(size_t)k * INNER + col];
    if (isv) Vg[bg * INNER + col] = f2bf(s);
    else     Kg[bg * INNER + col] = s;
}

// ---------------------------------------------------------------------------
// K2: attention — one wave per query, NO LDS, NO barriers.
// Lane l: head h=l>>3, rank r=l&7, owns j = 8l..8l+8.
// ---------------------------------------------------------------------------
__global__ __launch_bounds__(256) void attn_kernel(
    const float* __restrict__ Qb, const float* __restrict__ Kf,
    const float* __restrict__ Kg, const unsigned short* __restrict__ Vf,
    const unsigned short* __restrict__ Vg, const unsigned short* __restrict__ Tt,
    const int* __restrict__ topk, const float* __restrict__ rpe,
    const float* __restrict__ self_rpe, const float* __restrict__ distances,
    const float* __restrict__ log_sigma, const float* __restrict__ global_bias,
    unsigned short* __restrict__ obuf, unsigned short* __restrict__ rbar)
{
    const int lane = threadIdx.x & 63;
    const int w    = threadIdx.x >> 6;
    const int q    = blockIdx.x * 4 + w;
    const int b    = q >> 12;                 // L = 4096
    const int h    = lane >> 3;
    const int r    = lane & 7;

    // Q slice in registers
    const float4* qp = reinterpret_cast<const float4*>(&Qb[(size_t)q * INNER + lane * 8]);
    const float4 qa = qp[0], qb4 = qp[1];

    // t4[i] = t[h][r*4+i], from precomputed T (bf16)
    float t4[4];
    {
        ushort4_t tu = *reinterpret_cast<const ushort4_t*>(
            &Tt[(size_t)q * 256 + h * 32 + r * 4]);
        t4[0] = bf2f(tu[0]); t4[1] = bf2f(tu[1]);
        t4[2] = bf2f(tu[2]); t4[3] = bf2f(tu[3]);
    }

    int   tk = 0; float dl = 0.f;
    if (lane < KK) {
        tk = topk[q * KK + lane];
        dl = distances[q * KK + lane];
    }
    const float sig2  = __expf(2.f * log_sigma[h]);
    const float gbias = global_bias[0];

    // -------- logits --------
    float lg[3] = { -1e30f, -1e30f, -1e30f };  // lane owns c = r, r+8, r+16
    #pragma unroll
    for (int c = 0; c < CC; ++c) {
        const float* base;
        if (c == 0)       base = &Kf[(size_t)q * INNER];
        else if (c < 17)  { const int idx = __shfl(tk, c - 1);
                            base = &Kf[(size_t)(b * LL + idx) * INNER]; }
        else              base = &Kg[(size_t)(b * GG + (c - 17)) * INNER];
        const float4* kp = reinterpret_cast<const float4*>(base + lane * 8);
        const float4 ka = kp[0], kb = kp[1];
        float part = ka.x*qa.x + ka.y*qa.y + ka.z*qa.z + ka.w*qa.w
                   + kb.x*qb4.x + kb.y*qb4.y + kb.z*qb4.z + kb.w*qb4.w;
        if (c < 17) {
            const float* rp_ = (c == 0) ? &self_rpe[(size_t)q * PE]
                                        : &rpe[((size_t)q * KK + (c - 1)) * PE];
            const float4 r4 = *reinterpret_cast<const float4*>(rp_ + r * 4);
            part += r4.x*t4[0] + r4.y*t4[1] + r4.z*t4[2] + r4.w*t4[3];
        }
        part += __shfl_xor(part, 1);
        part += __shfl_xor(part, 2);
        part += __shfl_xor(part, 4);
        float bias;
        if (c == 0)      bias = 0.f;
        else if (c < 17) { const float d = __shfl(dl, c - 1);
                           bias = -(d * d) / (2.f * sig2); }
        else             bias = gbias;
        if (r == (c & 7)) lg[c >> 3] = part * SCALE + bias;
    }

    // -------- softmax over the 8-lane head group --------
    float mx = fmaxf(fmaxf(lg[0], lg[1]), lg[2]);
    mx = fmaxf(mx, __shfl_xor(mx, 1));
    mx = fmaxf(mx, __shfl_xor(mx, 2));
    mx = fmaxf(mx, __shfl_xor(mx, 4));
    const float e0 = __expf(lg[0] - mx);
    const float e1 = __expf(lg[1] - mx);
    const float e2 = __expf(lg[2] - mx);
    float s = e0 + e1 + e2;
    s += __shfl_xor(s, 1);
    s += __shfl_xor(s, 2);
    s += __shfl_xor(s, 4);
    const float inv = 1.f / s;
    float wloc[3] = { e0 * inv, e1 * inv, e2 * inv };

    // -------- weighted V (bf16) + rbar accumulation --------
    float4 acc_a = {0.f,0.f,0.f,0.f}, acc_b = {0.f,0.f,0.f,0.f};
    float rb4[4] = {0.f, 0.f, 0.f, 0.f};
    #pragma unroll
    for (int c = 0; c < CC; ++c) {
        const unsigned short* vb;
        if (c == 0)       vb = &Vf[(size_t)q * INNER];
        else if (c < 17)  { const int idx = __shfl(tk, c - 1);
                            vb = &Vf[(size_t)(b * LL + idx) * INNER]; }
        else              vb = &Vg[(size_t)(b * GG + (c - 17)) * INNER];
        ushort8_t vv = *reinterpret_cast<const ushort8_t*>(vb + lane * 8);
        const float wv = __shfl(wloc[c >> 3], (lane & 56) | (c & 7));
        acc_a.x += wv * bf2f(vv[0]); acc_a.y += wv * bf2f(vv[1]);
        acc_a.z += wv * bf2f(vv[2]); acc_a.w += wv * bf2f(vv[3]);
        acc_b.x += wv * bf2f(vv[4]); acc_b.y += wv * bf2f(vv[5]);
        acc_b.z += wv * bf2f(vv[6]); acc_b.w += wv * bf2f(vv[7]);
        if (c < 17) {
            const float* rp_ = (c == 0) ? &self_rpe[(size_t)q * PE]
                                        : &rpe[((size_t)q * KK + (c - 1)) * PE];
            const float4 r4 = *reinterpret_cast<const float4*>(rp_ + r * 4);
            rb4[0] += wv * r4.x; rb4[1] += wv * r4.y;
            rb4[2] += wv * r4.z; rb4[3] += wv * r4.w;
        }
    }

    // write rbar (lane-distributed, bf16) and obuf (bf16)
    ushort4_t ru = { f2bf(rb4[0]), f2bf(rb4[1]), f2bf(rb4[2]), f2bf(rb4[3]) };
    *reinterpret_cast<ushort4_t*>(&rbar[(size_t)q * 256 + h * 32 + r * 4]) = ru;
    ushort8_t ou = { f2bf(acc_a.x), f2bf(acc_a.y), f2bf(acc_a.z), f2bf(acc_a.w),
                     f2bf(acc_b.x), f2bf(acc_b.y), f2bf(acc_b.z), f2bf(acc_b.w) };
    *reinterpret_cast<ushort8_t*>(&obuf[(size_t)q * INNER + lane * 8]) = ou;
}

// ---------------------------------------------------------------------------
// K3: out[M,256] = obuf[M,512]@Wo + rbar[M,256]@M2 + bo   (K = 768)
// ---------------------------------------------------------------------------
__global__ __launch_bounds__(256) void gemm_out(
    const unsigned short* __restrict__ obuf, const unsigned short* __restrict__ rbar,
    const float* __restrict__ Wo, const float* __restrict__ M2,
    const float* __restrict__ bo, float* __restrict__ Out)
{
    const int bm = blockIdx.x;
    const int bn = blockIdx.y;          // 0..3
    const int col0 = bn * 64;

    __shared__ float As[16][64 + 1];
    __shared__ float Bs[16][64];

    const int tid = threadIdx.x;
    const int tx = tid & 15;
    const int ty = tid >> 4;
    const int m0 = bm * 64;

    float acc[4][4] = {};

    const int ar = tid >> 2;
    const int ac = (tid & 3) << 2;
    const int br = tid >> 4;
    const int bc = (tid & 15) << 2;

    for (int k0 = 0; k0 < 768; k0 += 16) {
        const unsigned short* asrc;
        const float* brow;
        int ld, koff;
        if (k0 < 512) { asrc = obuf; ld = INNER; koff = k0;
                        brow = &Wo[(size_t)(k0 + br) * DD]; }
        else          { asrc = rbar; ld = 256;   koff = k0 - 512;
                        brow = &M2[(size_t)(k0 - 512 + br) * DD]; }
        ushort4_t au = *reinterpret_cast<const ushort4_t*>(
            &asrc[(size_t)(m0 + ar) * ld + koff + ac]);
        As[ac + 0][ar] = bf2f(au[0]); As[ac + 1][ar] = bf2f(au[1]);
        As[ac + 2][ar] = bf2f(au[2]); As[ac + 3][ar] = bf2f(au[3]);
        float4 bv = *reinterpret_cast<const float4*>(&brow[col0 + bc]);
        *reinterpret_cast<float4*>(&Bs[br][bc]) = bv;
        __syncthreads();
        #pragma unroll
        for (int kk = 0; kk < 16; ++kk) {
            float a[4], b[4];
            #pragma unroll
            for (int i = 0; i < 4; ++i) a[i] = As[kk][ty * 4 + i];
            #pragma unroll
            for (int j = 0; j < 4; ++j) b[j] = Bs[kk][tx * 4 + j];
            #pragma unroll
            for (int i = 0; i < 4; ++i)
                #pragma unroll
                for (int j = 0; j < 4; ++j)
                    acc[i][j] += a[i] * b[j];
        }
        __syncthreads();
    }
    #pragma unroll
    for (int i = 0; i < 4; ++i) {
        const int m = m0 + ty * 4 + i;
        #pragma unroll
        for (int j = 0; j < 4; ++j) {
            const int n = col0 + tx * 4 + j;
            Out[(size_t)m * DD + n] = acc[i][j] + bo[n];
        }
    }
}

// ---------------------------------------------------------------------------
extern "C" void kernel_launch(void* const* d_in, const int* in_sizes, int n_in,
                              void* d_out, int out_size, void* d_ws, size_t ws_size,
                              hipStream_t stream)
{
    const float* spatial     = (const float*)d_in[0];
    const int*   topk        = (const int*)  d_in[1];
    const float* rpe         = (const float*)d_in[2];
    const float* self_rpe    = (const float*)d_in[3];
    const float* distances   = (const float*)d_in[4];
    const float* gl          = (const float*)d_in[5];
    const float* Wq          = (const float*)d_in[6];
    const float* Wk          = (const float*)d_in[7];
    const float* Wv          = (const float*)d_in[8];
    const float* Wo          = (const float*)d_in[9];
    const float* bo          = (const float*)d_in[10];
    const float* log_sigma   = (const float*)d_in[11];
    const float* global_bias = (const float*)d_in[12];
    float* out = (float*)d_out;

    float* ws = (float*)d_ws;
    const size_t SEGF = (size_t)MM * INNER;          // 4,194,304 floats

    float* Qb = ws;                                  // fp32 [M,512]
    float* Kf = ws + SEGF;                           // fp32 [M,512]
    float* Kg = ws + 2 * SEGF;                       // fp32 [8,512]
    float* A  = Kg + BB * GG * INNER;                // fp32 [256,256]
    float* M2 = A + 256 * 256;                       // fp32 [256,256]
    unsigned short* Vf   = (unsigned short*)(M2 + 256 * 256);  // bf16 [M,512]
    unsigned short* Tt   = Vf + (size_t)MM * INNER;            // bf16 [M,256]
    unsigned short* obuf = Tt + (size_t)MM * 256;              // bf16 [M,512]
    unsigned short* rbar = obuf + (size_t)MM * INNER;          // bf16 [M,256]
    unsigned short* Vg   = rbar + (size_t)MM * 256;            // bf16 [8,512]

    prep_A <<<256, 256, 0, stream>>>(Wq, Wk, A);
    prep_M2<<<256, 256, 0, stream>>>(Wv, Wo, M2);
    gemm_qkvt<<<dim3(MM / 64, 28), 256, 0, stream>>>(
        spatial, Wq, Wk, Wv, A, Qb, Kf, Vf, Tt);
    gemm_globals<<<dim3(BB * GG, 4), 256, 0, stream>>>(gl, Wk, Wv, Kg, Vg);
    attn_kernel<<<MM / 4, 256, 0, stream>>>(
        Qb, Kf, Kg, Vf, Vg, Tt, topk, rpe, self_rpe, distances,
        log_sigma, global_bias, obuf, rbar);
    gemm_out<<<dim3(MM / 64, DD / 64), 256, 0, stream>>>(
        obuf, rbar, Wo, M2, bo, out);
}

// Round 4
// 141.289 us; speedup vs baseline: 1.9633x; 1.9633x over previous
//
#include <hip/hip_runtime.h>
#include <hip/hip_bf16.h>

// Problem constants
#define BB 2
#define LL 4096
#define DD 256
#define KK 16
#define GG 4
#define HH 8
#define DH 64
#define PE 32
#define INNER 512          // H*DH
#define CC 21              // 1 + K + G
#define MM (BB*LL)         // 8192
#define SCALE 0.125f
#define NT1 1792           // QKVT GEMM N  (Q|K|V|T)
#define KT1 256
#define NT2 256            // out GEMM N
#define KT2 768

typedef unsigned short u16;
typedef __attribute__((ext_vector_type(8))) short bf16x8;
typedef __attribute__((ext_vector_type(4))) float f32x4;
typedef unsigned short ushort4_t __attribute__((ext_vector_type(4)));
typedef unsigned short ushort8_t __attribute__((ext_vector_type(8)));

static __device__ __forceinline__ float bf2f(unsigned short u) {
    return __uint_as_float(((unsigned)u) << 16);
}
static __device__ __forceinline__ unsigned short f2bf(float f) {
    unsigned u = __float_as_uint(f);
    unsigned r = u + 0x7fffu + ((u >> 16) & 1u);   // RNE
    return (unsigned short)(r >> 16);
}
static __device__ __forceinline__ void gld_lds16(const void* g, void* l) {
    __builtin_amdgcn_global_load_lds(
        (const __attribute__((address_space(1))) unsigned int*)g,
        (__attribute__((address_space(3))) unsigned int*)l, 16, 0, 0);
}

// ---------------------------------------------------------------------------
// prep_A: A[e, h*32+p] = sum_d Wq[e, h*64+d] * Wk[256+p, h*64+d]   (256x256)
// ---------------------------------------------------------------------------
__global__ __launch_bounds__(256) void prep_A(
    const float* __restrict__ Wq, const float* __restrict__ Wk,
    float* __restrict__ A)
{
    const int e = blockIdx.x;
    const int tid = threadIdx.x;
    __shared__ float qrow[INNER];
    qrow[tid]       = Wq[e * INNER + tid];
    qrow[tid + 256] = Wq[e * INNER + 256 + tid];
    __syncthreads();
    const int h = tid >> 5, p = tid & 31;
    const float* __restrict__ wr = &Wk[(size_t)(DD + p) * INNER + h * DH];
    const float* __restrict__ qh = &qrow[h * DH];
    float s = 0.f;
    #pragma unroll 8
    for (int d = 0; d < DH; ++d) s += wr[d] * qh[d];
    A[e * 256 + tid] = s;
}

// ---------------------------------------------------------------------------
// prep_M2: M2[h*32+p, n] = sum_d Wv[256+p, h*64+d] * Wo[h*64+d, n]  (256x256)
// ---------------------------------------------------------------------------
__global__ __launch_bounds__(256) void prep_M2(
    const float* __restrict__ Wv, const float* __restrict__ Wo,
    float* __restrict__ M2)
{
    const int hp = blockIdx.x;
    const int h = hp >> 5, p = hp & 31;
    const int tid = threadIdx.x;
    __shared__ float vrow[DH];
    if (tid < DH) vrow[tid] = Wv[(size_t)(DD + p) * INNER + h * DH + tid];
    __syncthreads();
    float s = 0.f;
    #pragma unroll 8
    for (int d = 0; d < DH; ++d) s += vrow[d] * Wo[(size_t)(h * DH + d) * DD + tid];
    M2[hp * 256 + tid] = s;
}

// ---------------------------------------------------------------------------
// cast_spatial: fp32 [M,256] -> bf16
// ---------------------------------------------------------------------------
__global__ __launch_bounds__(256) void cast_spatial(
    const float* __restrict__ in, u16* __restrict__ out)
{
    const size_t i = ((size_t)blockIdx.x * 256 + threadIdx.x) * 8;
    float4 a = *reinterpret_cast<const float4*>(&in[i]);
    float4 b = *reinterpret_cast<const float4*>(&in[i + 4]);
    ushort8_t v = { f2bf(a.x), f2bf(a.y), f2bf(a.z), f2bf(a.w),
                    f2bf(b.x), f2bf(b.y), f2bf(b.z), f2bf(b.w) };
    *reinterpret_cast<ushort8_t*>(&out[i]) = v;
}

// ---------------------------------------------------------------------------
// prep_wcat: Wt[n][k] = [Wq | Wk_f | Wv_f | A](k, n)  -> bf16 [1792][256]
// ---------------------------------------------------------------------------
__global__ __launch_bounds__(256) void prep_wcat(
    const float* __restrict__ Wq, const float* __restrict__ Wk,
    const float* __restrict__ Wv, const float* __restrict__ A,
    u16* __restrict__ Wt)
{
    const int n = blockIdx.x;
    const int k = threadIdx.x;
    float v;
    if (n < 512)       v = Wq[(size_t)k * INNER + n];
    else if (n < 1024) v = Wk[(size_t)k * INNER + (n - 512)];
    else if (n < 1536) v = Wv[(size_t)k * INNER + (n - 1024)];
    else               v = A[(size_t)k * 256 + (n - 1536)];
    Wt[(size_t)n * 256 + k] = f2bf(v);
}

// ---------------------------------------------------------------------------
// prep_wout: Wot[n][k] = [Wo ; M2](k, n)  -> bf16 [256][768]
// ---------------------------------------------------------------------------
__global__ __launch_bounds__(256) void prep_wout(
    const float* __restrict__ Wo, const float* __restrict__ M2,
    u16* __restrict__ Wot)
{
    const int n = blockIdx.x;
    for (int k = threadIdx.x; k < KT2; k += 256) {
        float v = (k < 512) ? Wo[(size_t)k * DD + n] : M2[(size_t)(k - 512) * DD + n];
        Wot[(size_t)n * KT2 + k] = f2bf(v);
    }
}

// ---------------------------------------------------------------------------
// mfma_gemm: C[M, NTOT-tile] = A[M, KT] @ Bt[NTOT, KT]^T   (bf16 in, fp32 acc)
// BM=128, BK=64, 4 waves (2x2). BN template (128 or 64).
// m97-style: global_load_lds width16 into linear LDS, ds_read_b128 fragments.
// ---------------------------------------------------------------------------
template<int KT, int LDA, int NTOT, int BN, bool F32OUT>
__global__ __launch_bounds__(256) void mfma_gemm(
    const u16* __restrict__ A, const u16* __restrict__ Bt,
    u16* __restrict__ outB, float* __restrict__ outF,
    const float* __restrict__ bias)
{
    constexpr int WNT = BN / 2;       // per-wave n-tile
    constexpr int BJ  = WNT / 16;     // n fragments per wave
    constexpr int BCH = BN / 8;       // B-tile 1KB chunks

    __shared__ u16 As[128 * 64];
    __shared__ u16 Bs[BN * 64];

    const int tid  = threadIdx.x;
    const int lane = tid & 63;
    const int w    = tid >> 6;
    const int wr   = w >> 1, wc = w & 1;
    const int m0 = blockIdx.x * 128;
    const int n0 = blockIdx.y * BN;
    const int fr = lane & 15, fq = lane >> 4;

    f32x4 acc[4][BJ];
    #pragma unroll
    for (int i = 0; i < 4; ++i)
        #pragma unroll
        for (int j = 0; j < BJ; ++j)
            acc[i][j] = (f32x4){0.f, 0.f, 0.f, 0.f};

    for (int t = 0; t < KT / 64; ++t) {
        const int k0 = t * 64;
        #pragma unroll
        for (int cc = 0; cc < 4; ++cc) {       // A: 16 chunks, 4 per wave
            const int chunk = w + cc * 4;
            gld_lds16(A + (size_t)(m0 + chunk * 8 + (lane >> 3)) * LDA + k0 + (lane & 7) * 8,
                      (char*)&As[0] + chunk * 1024);
        }
        #pragma unroll
        for (int cc = 0; cc < BCH / 4; ++cc) { // B: BCH chunks
            const int chunk = w + cc * 4;
            gld_lds16(Bt + (size_t)(n0 + chunk * 8 + (lane >> 3)) * KT + k0 + (lane & 7) * 8,
                      (char*)&Bs[0] + chunk * 1024);
        }
        __syncthreads();
        #pragma unroll
        for (int ks = 0; ks < 2; ++ks) {
            bf16x8 av[4], bv[BJ];
            #pragma unroll
            for (int i = 0; i < 4; ++i)
                av[i] = *reinterpret_cast<const bf16x8*>(
                    &As[(wr * 64 + i * 16 + fr) * 64 + ks * 32 + fq * 8]);
            #pragma unroll
            for (int j = 0; j < BJ; ++j)
                bv[j] = *reinterpret_cast<const bf16x8*>(
                    &Bs[(wc * WNT + j * 16 + fr) * 64 + ks * 32 + fq * 8]);
            #pragma unroll
            for (int i = 0; i < 4; ++i)
                #pragma unroll
                for (int j = 0; j < BJ; ++j)
                    acc[i][j] = __builtin_amdgcn_mfma_f32_16x16x32_bf16(
                        av[i], bv[j], acc[i][j], 0, 0, 0);
        }
        __syncthreads();
    }

    #pragma unroll
    for (int i = 0; i < 4; ++i)
        #pragma unroll
        for (int j = 0; j < BJ; ++j)
            #pragma unroll
            for (int rgi = 0; rgi < 4; ++rgi) {
                const int row = m0 + wr * 64 + i * 16 + fq * 4 + rgi;
                const int col = n0 + wc * WNT + j * 16 + fr;
                if constexpr (F32OUT)
                    outF[(size_t)row * NTOT + col] = acc[i][j][rgi] + bias[col];
                else
                    outB[(size_t)row * NTOT + col] = f2bf(acc[i][j][rgi]);
            }
}

// ---------------------------------------------------------------------------
// gemm_globals: Kg/Vg bf16 [8][512]
// ---------------------------------------------------------------------------
__global__ __launch_bounds__(256) void gemm_globals(
    const float* __restrict__ gl, const float* __restrict__ Wk,
    const float* __restrict__ Wv, u16* __restrict__ Kg, u16* __restrict__ Vg)
{
    const int bg  = blockIdx.x;
    const int tid = threadIdx.x;
    const int col = blockIdx.y * 128 + (tid & 127);
    const bool isv = tid >= 128;
    const float* __restrict__ W = isv ? Wv : Wk;
    const float* __restrict__ x = &gl[bg * DD];
    float s = 0.f;
    #pragma unroll 4
    for (int k = 0; k < DD; ++k) s += x[k] * W[(size_t)k * INNER + col];
    if (isv) Vg[bg * INNER + col] = f2bf(s);
    else     Kg[bg * INNER + col] = f2bf(s);
}

// ---------------------------------------------------------------------------
// attn: one wave per query.  X = [Q|K|V|T] bf16 rows of 1792.
// Lane l: head h=l>>3, rank r=l&7, owns j = 8l..8l+8.
// ---------------------------------------------------------------------------
__global__ __launch_bounds__(256) void attn_kernel(
    const u16* __restrict__ X, const u16* __restrict__ Kg,
    const u16* __restrict__ Vg, const int* __restrict__ topk,
    const float* __restrict__ rpe, const float* __restrict__ self_rpe,
    const float* __restrict__ distances, const float* __restrict__ log_sigma,
    const float* __restrict__ global_bias, u16* __restrict__ ob2)
{
    const int lane = threadIdx.x & 63;
    const int w    = threadIdx.x >> 6;
    const int q    = blockIdx.x * 4 + w;
    const int b    = q >> 12;
    const int h    = lane >> 3;
    const int r    = lane & 7;

    // Q slice (bf16 -> f32 regs)
    float qf[8];
    {
        ushort8_t qv = *reinterpret_cast<const ushort8_t*>(&X[(size_t)q * NT1 + lane * 8]);
        #pragma unroll
        for (int j = 0; j < 8; ++j) qf[j] = bf2f(qv[j]);
    }
    // t4
    float t4[4];
    {
        ushort4_t tu = *reinterpret_cast<const ushort4_t*>(
            &X[(size_t)q * NT1 + 1536 + h * 32 + r * 4]);
        t4[0] = bf2f(tu[0]); t4[1] = bf2f(tu[1]);
        t4[2] = bf2f(tu[2]); t4[3] = bf2f(tu[3]);
    }

    int   tk = 0; float dl = 0.f;
    if (lane < KK) {
        tk = topk[q * KK + lane];
        dl = distances[q * KK + lane];
    }
    const float sig2  = __expf(2.f * log_sigma[h]);
    const float gbias = global_bias[0];

    // -------- logits --------
    float lg[3] = { -1e30f, -1e30f, -1e30f };
    #pragma unroll
    for (int c = 0; c < CC; ++c) {
        const u16* kb;
        if (c == 0)       kb = &X[(size_t)q * NT1 + 512];
        else if (c < 17)  { const int idx = __shfl(tk, c - 1);
                            kb = &X[(size_t)(b * LL + idx) * NT1 + 512]; }
        else              kb = &Kg[(size_t)(b * GG + (c - 17)) * INNER];
        ushort8_t kv = *reinterpret_cast<const ushort8_t*>(kb + lane * 8);
        float part = bf2f(kv[0])*qf[0] + bf2f(kv[1])*qf[1]
                   + bf2f(kv[2])*qf[2] + bf2f(kv[3])*qf[3]
                   + bf2f(kv[4])*qf[4] + bf2f(kv[5])*qf[5]
                   + bf2f(kv[6])*qf[6] + bf2f(kv[7])*qf[7];
        if (c < 17) {
            const float* rp_ = (c == 0) ? &self_rpe[(size_t)q * PE]
                                        : &rpe[((size_t)q * KK + (c - 1)) * PE];
            const float4 r4 = *reinterpret_cast<const float4*>(rp_ + r * 4);
            part += r4.x*t4[0] + r4.y*t4[1] + r4.z*t4[2] + r4.w*t4[3];
        }
        part += __shfl_xor(part, 1);
        part += __shfl_xor(part, 2);
        part += __shfl_xor(part, 4);
        float bias;
        if (c == 0)      bias = 0.f;
        else if (c < 17) { const float d = __shfl(dl, c - 1);
                           bias = -(d * d) / (2.f * sig2); }
        else             bias = gbias;
        if (r == (c & 7)) lg[c >> 3] = part * SCALE + bias;
    }

    // -------- softmax (8-lane head group) --------
    float mx = fmaxf(fmaxf(lg[0], lg[1]), lg[2]);
    mx = fmaxf(mx, __shfl_xor(mx, 1));
    mx = fmaxf(mx, __shfl_xor(mx, 2));
    mx = fmaxf(mx, __shfl_xor(mx, 4));
    const float e0 = __expf(lg[0] - mx);
    const float e1 = __expf(lg[1] - mx);
    const float e2 = __expf(lg[2] - mx);
    float s = e0 + e1 + e2;
    s += __shfl_xor(s, 1);
    s += __shfl_xor(s, 2);
    s += __shfl_xor(s, 4);
    const float inv = 1.f / s;
    float wloc[3] = { e0 * inv, e1 * inv, e2 * inv };

    // -------- weighted V + rbar --------
    float4 acc_a = {0.f,0.f,0.f,0.f}, acc_b = {0.f,0.f,0.f,0.f};
    float rb4[4] = {0.f, 0.f, 0.f, 0.f};
    #pragma unroll
    for (int c = 0; c < CC; ++c) {
        const u16* vb;
        if (c == 0)       vb = &X[(size_t)q * NT1 + 1024];
        else if (c < 17)  { const int idx = __shfl(tk, c - 1);
                            vb = &X[(size_t)(b * LL + idx) * NT1 + 1024]; }
        else              vb = &Vg[(size_t)(b * GG + (c - 17)) * INNER];
        ushort8_t vv = *reinterpret_cast<const ushort8_t*>(vb + lane * 8);
        const float wv = __shfl(wloc[c >> 3], (lane & 56) | (c & 7));
        acc_a.x += wv * bf2f(vv[0]); acc_a.y += wv * bf2f(vv[1]);
        acc_a.z += wv * bf2f(vv[2]); acc_a.w += wv * bf2f(vv[3]);
        acc_b.x += wv * bf2f(vv[4]); acc_b.y += wv * bf2f(vv[5]);
        acc_b.z += wv * bf2f(vv[6]); acc_b.w += wv * bf2f(vv[7]);
        if (c < 17) {
            const float* rp_ = (c == 0) ? &self_rpe[(size_t)q * PE]
                                        : &rpe[((size_t)q * KK + (c - 1)) * PE];
            const float4 r4 = *reinterpret_cast<const float4*>(rp_ + r * 4);
            rb4[0] += wv * r4.x; rb4[1] += wv * r4.y;
            rb4[2] += wv * r4.z; rb4[3] += wv * r4.w;
        }
    }

    ushort4_t ru = { f2bf(rb4[0]), f2bf(rb4[1]), f2bf(rb4[2]), f2bf(rb4[3]) };
    *reinterpret_cast<ushort4_t*>(&ob2[(size_t)q * KT2 + 512 + h * 32 + r * 4]) = ru;
    ushort8_t ou = { f2bf(acc_a.x), f2bf(acc_a.y), f2bf(acc_a.z), f2bf(acc_a.w),
                     f2bf(acc_b.x), f2bf(acc_b.y), f2bf(acc_b.z), f2bf(acc_b.w) };
    *reinterpret_cast<ushort8_t*>(&ob2[(size_t)q * KT2 + lane * 8]) = ou;
}

// ---------------------------------------------------------------------------
extern "C" void kernel_launch(void* const* d_in, const int* in_sizes, int n_in,
                              void* d_out, int out_size, void* d_ws, size_t ws_size,
                              hipStream_t stream)
{
    const float* spatial     = (const float*)d_in[0];
    const int*   topk        = (const int*)  d_in[1];
    const float* rpe         = (const float*)d_in[2];
    const float* self_rpe    = (const float*)d_in[3];
    const float* distances   = (const float*)d_in[4];
    const float* gl          = (const float*)d_in[5];
    const float* Wq          = (const float*)d_in[6];
    const float* Wk          = (const float*)d_in[7];
    const float* Wv          = (const float*)d_in[8];
    const float* Wo          = (const float*)d_in[9];
    const float* bo          = (const float*)d_in[10];
    const float* log_sigma   = (const float*)d_in[11];
    const float* global_bias = (const float*)d_in[12];
    float* out = (float*)d_out;

    char* p = (char*)d_ws;
    float* A   = (float*)p;  p += (size_t)256 * 256 * 4;
    float* M2  = (float*)p;  p += (size_t)256 * 256 * 4;
    u16* Sb    = (u16*)p;    p += (size_t)MM * DD * 2;
    u16* Wt    = (u16*)p;    p += (size_t)NT1 * KT1 * 2;
    u16* Wot   = (u16*)p;    p += (size_t)NT2 * KT2 * 2;
    u16* X     = (u16*)p;    p += (size_t)MM * NT1 * 2;
    u16* ob2   = (u16*)p;    p += (size_t)MM * KT2 * 2;
    u16* Kg    = (u16*)p;    p += (size_t)BB * GG * INNER * 2;
    u16* Vg    = (u16*)p;    p += (size_t)BB * GG * INNER * 2;

    prep_A <<<256, 256, 0, stream>>>(Wq, Wk, A);
    prep_M2<<<256, 256, 0, stream>>>(Wv, Wo, M2);
    cast_spatial<<<MM * DD / (256 * 8), 256, 0, stream>>>(spatial, Sb);
    prep_wcat<<<NT1, 256, 0, stream>>>(Wq, Wk, Wv, A, Wt);
    prep_wout<<<NT2, 256, 0, stream>>>(Wo, M2, Wot);
    gemm_globals<<<dim3(BB * GG, 4), 256, 0, stream>>>(gl, Wk, Wv, Kg, Vg);

    mfma_gemm<KT1, 256, NT1, 128, false><<<dim3(MM / 128, NT1 / 128), 256, 0, stream>>>(
        Sb, Wt, X, nullptr, nullptr);

    attn_kernel<<<MM / 4, 256, 0, stream>>>(
        X, Kg, Vg, topk, rpe, self_rpe, distances, log_sigma, global_bias, ob2);

    mfma_gemm<KT2, KT2, NT2, 64, true><<<dim3(MM / 128, NT2 / 64), 256, 0, stream>>>(
        ob2, Wot, nullptr, out, bo);
}

// Round 5
// 118.430 us; speedup vs baseline: 2.3422x; 1.1930x over previous
//
#include <hip/hip_runtime.h>
#include <hip/hip_bf16.h>

// Problem constants
#define BB 2
#define LL 4096
#define DD 256
#define KK 16
#define GG 4
#define HH 8
#define DH 64
#define PE 32
#define INNER 512          // H*DH
#define CC 21              // 1 + K + G
#define MM (BB*LL)         // 8192
#define SCALE 0.125f
#define NT1 1792           // QKVT GEMM N  (Q|K|V|T)
#define KT1 256
#define NT2 256            // out GEMM N
#define KT2 768

typedef unsigned short u16;
typedef __attribute__((ext_vector_type(8))) short bf16x8;
typedef __attribute__((ext_vector_type(4))) float f32x4;
typedef unsigned short ushort4_t __attribute__((ext_vector_type(4)));
typedef unsigned short ushort8_t __attribute__((ext_vector_type(8)));

static __device__ __forceinline__ float bf2f(unsigned short u) {
    return __uint_as_float(((unsigned)u) << 16);
}
static __device__ __forceinline__ unsigned short f2bf(float f) {
    unsigned u = __float_as_uint(f);
    unsigned r = u + 0x7fffu + ((u >> 16) & 1u);   // RNE
    return (unsigned short)(r >> 16);
}
static __device__ __forceinline__ void gld_lds16(const void* g, void* l) {
    __builtin_amdgcn_global_load_lds(
        (const __attribute__((address_space(1))) unsigned int*)g,
        (__attribute__((address_space(3))) unsigned int*)l, 16, 0, 0);
}

// ---------------------------------------------------------------------------
// prep_A: A[e, h*32+p] = sum_d Wq[e, h*64+d] * Wk[256+p, h*64+d]   (256x256)
// ---------------------------------------------------------------------------
__global__ __launch_bounds__(256) void prep_A(
    const float* __restrict__ Wq, const float* __restrict__ Wk,
    float* __restrict__ A)
{
    const int e = blockIdx.x;
    const int tid = threadIdx.x;
    __shared__ float qrow[INNER];
    qrow[tid]       = Wq[e * INNER + tid];
    qrow[tid + 256] = Wq[e * INNER + 256 + tid];
    __syncthreads();
    const int h = tid >> 5, p = tid & 31;
    const float* __restrict__ wr = &Wk[(size_t)(DD + p) * INNER + h * DH];
    const float* __restrict__ qh = &qrow[h * DH];
    float s = 0.f;
    #pragma unroll 8
    for (int d = 0; d < DH; ++d) s += wr[d] * qh[d];
    A[e * 256 + tid] = s;
}

// ---------------------------------------------------------------------------
// prep_M2: M2[h*32+p, n] = sum_d Wv[256+p, h*64+d] * Wo[h*64+d, n]  (256x256)
// ---------------------------------------------------------------------------
__global__ __launch_bounds__(256) void prep_M2(
    const float* __restrict__ Wv, const float* __restrict__ Wo,
    float* __restrict__ M2)
{
    const int hp = blockIdx.x;
    const int h = hp >> 5, p = hp & 31;
    const int tid = threadIdx.x;
    __shared__ float vrow[DH];
    if (tid < DH) vrow[tid] = Wv[(size_t)(DD + p) * INNER + h * DH + tid];
    __syncthreads();
    float s = 0.f;
    #pragma unroll 8
    for (int d = 0; d < DH; ++d) s += vrow[d] * Wo[(size_t)(h * DH + d) * DD + tid];
    M2[hp * 256 + tid] = s;
}

// ---------------------------------------------------------------------------
// cast_spatial: fp32 [M,256] -> bf16
// ---------------------------------------------------------------------------
__global__ __launch_bounds__(256) void cast_spatial(
    const float* __restrict__ in, u16* __restrict__ out)
{
    const size_t i = ((size_t)blockIdx.x * 256 + threadIdx.x) * 8;
    float4 a = *reinterpret_cast<const float4*>(&in[i]);
    float4 b = *reinterpret_cast<const float4*>(&in[i + 4]);
    ushort8_t v = { f2bf(a.x), f2bf(a.y), f2bf(a.z), f2bf(a.w),
                    f2bf(b.x), f2bf(b.y), f2bf(b.z), f2bf(b.w) };
    *reinterpret_cast<ushort8_t*>(&out[i]) = v;
}

// ---------------------------------------------------------------------------
// prep_wcat_t: tiled transpose.  Wt[n][k] = [Wq|Wk_f|Wv_f|A](k,n) bf16 [1792][256]
// grid (28, 4), 64x64 tiles, coalesced both sides.
// ---------------------------------------------------------------------------
__global__ __launch_bounds__(256) void prep_wcat_t(
    const float* __restrict__ Wq, const float* __restrict__ Wk,
    const float* __restrict__ Wv, const float* __restrict__ A,
    u16* __restrict__ Wt)
{
    const int n0 = blockIdx.x * 64;
    const int k0 = blockIdx.y * 64;
    const float* src; int ld, nloc;
    if (n0 < 512)       { src = Wq; ld = INNER; nloc = n0; }
    else if (n0 < 1024) { src = Wk; ld = INNER; nloc = n0 - 512; }
    else if (n0 < 1536) { src = Wv; ld = INNER; nloc = n0 - 1024; }
    else                { src = A;  ld = 256;   nloc = n0 - 1536; }

    __shared__ float tile[64][65];
    const int tid = threadIdx.x;
    const int tk = tid >> 4;            // 0..15
    const int tn = (tid & 15) * 4;      // 0..60
    #pragma unroll
    for (int rep = 0; rep < 4; ++rep) {
        const int k = k0 + tk + rep * 16;
        float4 v = *reinterpret_cast<const float4*>(&src[(size_t)k * ld + nloc + tn]);
        tile[tk + rep * 16][tn + 0] = v.x; tile[tk + rep * 16][tn + 1] = v.y;
        tile[tk + rep * 16][tn + 2] = v.z; tile[tk + rep * 16][tn + 3] = v.w;
    }
    __syncthreads();
    const int wn = tid >> 2;            // 0..63
    const int wk = (tid & 3) * 16;      // 0,16,32,48
    ushort8_t o0, o1;
    #pragma unroll
    for (int i = 0; i < 8; ++i) o0[i] = f2bf(tile[wk + i][wn]);
    #pragma unroll
    for (int i = 0; i < 8; ++i) o1[i] = f2bf(tile[wk + 8 + i][wn]);
    u16* dst = &Wt[(size_t)(n0 + wn) * KT1 + k0 + wk];
    *reinterpret_cast<ushort8_t*>(dst)     = o0;
    *reinterpret_cast<ushort8_t*>(dst + 8) = o1;
}

// ---------------------------------------------------------------------------
// prep_wout_t: Wot[n][k] = [Wo ; M2](k, n) bf16 [256][768].  grid (4, 12).
// ---------------------------------------------------------------------------
__global__ __launch_bounds__(256) void prep_wout_t(
    const float* __restrict__ Wo, const float* __restrict__ M2,
    u16* __restrict__ Wot)
{
    const int n0 = blockIdx.x * 64;
    const int k0 = blockIdx.y * 64;
    const float* src; int krow;
    if (k0 < 512) { src = Wo; krow = k0; }
    else          { src = M2; krow = k0 - 512; }

    __shared__ float tile[64][65];
    const int tid = threadIdx.x;
    const int tk = tid >> 4;
    const int tn = (tid & 15) * 4;
    #pragma unroll
    for (int rep = 0; rep < 4; ++rep) {
        const int k = krow + tk + rep * 16;
        float4 v = *reinterpret_cast<const float4*>(&src[(size_t)k * DD + n0 + tn]);
        tile[tk + rep * 16][tn + 0] = v.x; tile[tk + rep * 16][tn + 1] = v.y;
        tile[tk + rep * 16][tn + 2] = v.z; tile[tk + rep * 16][tn + 3] = v.w;
    }
    __syncthreads();
    const int wn = tid >> 2;
    const int wk = (tid & 3) * 16;
    ushort8_t o0, o1;
    #pragma unroll
    for (int i = 0; i < 8; ++i) o0[i] = f2bf(tile[wk + i][wn]);
    #pragma unroll
    for (int i = 0; i < 8; ++i) o1[i] = f2bf(tile[wk + 8 + i][wn]);
    u16* dst = &Wot[(size_t)(n0 + wn) * KT2 + k0 + wk];
    *reinterpret_cast<ushort8_t*>(dst)     = o0;
    *reinterpret_cast<ushort8_t*>(dst + 8) = o1;
}

// ---------------------------------------------------------------------------
// mfma_gemm (unchanged, proven): C = A[M,KT] @ Bt[N,KT]^T, bf16 in / fp32 acc
// ---------------------------------------------------------------------------
template<int KT, int LDA, int NTOT, int BN, bool F32OUT>
__global__ __launch_bounds__(256) void mfma_gemm(
    const u16* __restrict__ A, const u16* __restrict__ Bt,
    u16* __restrict__ outB, float* __restrict__ outF,
    const float* __restrict__ bias)
{
    constexpr int WNT = BN / 2;
    constexpr int BJ  = WNT / 16;
    constexpr int BCH = BN / 8;

    __shared__ u16 As[128 * 64];
    __shared__ u16 Bs[BN * 64];

    const int tid  = threadIdx.x;
    const int lane = tid & 63;
    const int w    = tid >> 6;
    const int wr   = w >> 1, wc = w & 1;
    const int m0 = blockIdx.x * 128;
    const int n0 = blockIdx.y * BN;
    const int fr = lane & 15, fq = lane >> 4;

    f32x4 acc[4][BJ];
    #pragma unroll
    for (int i = 0; i < 4; ++i)
        #pragma unroll
        for (int j = 0; j < BJ; ++j)
            acc[i][j] = (f32x4){0.f, 0.f, 0.f, 0.f};

    for (int t = 0; t < KT / 64; ++t) {
        const int k0 = t * 64;
        #pragma unroll
        for (int cc = 0; cc < 4; ++cc) {
            const int chunk = w + cc * 4;
            gld_lds16(A + (size_t)(m0 + chunk * 8 + (lane >> 3)) * LDA + k0 + (lane & 7) * 8,
                      (char*)&As[0] + chunk * 1024);
        }
        #pragma unroll
        for (int cc = 0; cc < BCH / 4; ++cc) {
            const int chunk = w + cc * 4;
            gld_lds16(Bt + (size_t)(n0 + chunk * 8 + (lane >> 3)) * KT + k0 + (lane & 7) * 8,
                      (char*)&Bs[0] + chunk * 1024);
        }
        __syncthreads();
        #pragma unroll
        for (int ks = 0; ks < 2; ++ks) {
            bf16x8 av[4], bv[BJ];
            #pragma unroll
            for (int i = 0; i < 4; ++i)
                av[i] = *reinterpret_cast<const bf16x8*>(
                    &As[(wr * 64 + i * 16 + fr) * 64 + ks * 32 + fq * 8]);
            #pragma unroll
            for (int j = 0; j < BJ; ++j)
                bv[j] = *reinterpret_cast<const bf16x8*>(
                    &Bs[(wc * WNT + j * 16 + fr) * 64 + ks * 32 + fq * 8]);
            #pragma unroll
            for (int i = 0; i < 4; ++i)
                #pragma unroll
                for (int j = 0; j < BJ; ++j)
                    acc[i][j] = __builtin_amdgcn_mfma_f32_16x16x32_bf16(
                        av[i], bv[j], acc[i][j], 0, 0, 0);
        }
        __syncthreads();
    }

    #pragma unroll
    for (int i = 0; i < 4; ++i)
        #pragma unroll
        for (int j = 0; j < BJ; ++j)
            #pragma unroll
            for (int rgi = 0; rgi < 4; ++rgi) {
                const int row = m0 + wr * 64 + i * 16 + fq * 4 + rgi;
                const int col = n0 + wc * WNT + j * 16 + fr;
                if constexpr (F32OUT)
                    outF[(size_t)row * NTOT + col] = acc[i][j][rgi] + bias[col];
                else
                    outB[(size_t)row * NTOT + col] = f2bf(acc[i][j][rgi]);
            }
}

// ---------------------------------------------------------------------------
// gemm_globals: Kg/Vg bf16 [8][512]
// ---------------------------------------------------------------------------
__global__ __launch_bounds__(256) void gemm_globals(
    const float* __restrict__ gl, const float* __restrict__ Wk,
    const float* __restrict__ Wv, u16* __restrict__ Kg, u16* __restrict__ Vg)
{
    const int bg  = blockIdx.x;
    const int tid = threadIdx.x;
    const int col = blockIdx.y * 128 + (tid & 127);
    const bool isv = tid >= 128;
    const float* __restrict__ W = isv ? Wv : Wk;
    const float* __restrict__ x = &gl[bg * DD];
    float s = 0.f;
    #pragma unroll 4
    for (int k = 0; k < DD; ++k) s += x[k] * W[(size_t)k * INNER + col];
    if (isv) Vg[bg * INNER + col] = f2bf(s);
    else     Kg[bg * INNER + col] = f2bf(s);
}

// ---------------------------------------------------------------------------
// attn: one wave per query, FUSED single pass with online softmax.
// q is made wave-uniform (readfirstlane) so topk/distances become s_loads and
// all row bases are SGPR + lane-offset: no shfl in any address chain.
// Within each 8-lane head group the reduced logit is group-uniform, so the
// online (m, denom, rescale) state needs no broadcasts at all.
// ---------------------------------------------------------------------------
__global__ __launch_bounds__(256) void attn_kernel(
    const u16* __restrict__ X, const u16* __restrict__ Kg,
    const u16* __restrict__ Vg, const int* __restrict__ topk,
    const float* __restrict__ rpe, const float* __restrict__ self_rpe,
    const float* __restrict__ distances, const float* __restrict__ log_sigma,
    const float* __restrict__ global_bias, u16* __restrict__ ob2)
{
    const int lane = threadIdx.x & 63;
    const int q = __builtin_amdgcn_readfirstlane(blockIdx.x * 4 + (threadIdx.x >> 6));
    const int b = q >> 12;
    const int h = lane >> 3;
    const int r = lane & 7;
    const int qk = q * KK;
    const size_t bL = (size_t)b * LL;
    const int bG = b * GG;

    // Q slice (bf16 -> f32 regs)
    float qf[8];
    {
        ushort8_t qv = *reinterpret_cast<const ushort8_t*>(&X[(size_t)q * NT1 + lane * 8]);
        #pragma unroll
        for (int j = 0; j < 8; ++j) qf[j] = bf2f(qv[j]);
    }
    // t4
    float t4[4];
    {
        ushort4_t tu = *reinterpret_cast<const ushort4_t*>(
            &X[(size_t)q * NT1 + 1536 + h * 32 + r * 4]);
        t4[0] = bf2f(tu[0]); t4[1] = bf2f(tu[1]);
        t4[2] = bf2f(tu[2]); t4[3] = bf2f(tu[3]);
    }

    const float inv2sig = 0.5f * __expf(-2.f * log_sigma[h]);
    const float gbias   = global_bias[0];

    float m = -1e30f, denom = 0.f;
    float acc[8] = {0.f,0.f,0.f,0.f,0.f,0.f,0.f,0.f};
    float rb[4]  = {0.f,0.f,0.f,0.f};

    #pragma unroll
    for (int c = 0; c < CC; ++c) {
        const u16 *kb, *vb;
        const float* rp_ = nullptr;
        float biasc;
        if (c == 0) {
            kb = &X[(size_t)q * NT1 + 512]; vb = &X[(size_t)q * NT1 + 1024];
            rp_ = &self_rpe[(size_t)q * PE];
            biasc = 0.f;
        } else if (c < 17) {
            const int idx = topk[qk + c - 1];              // s_load (uniform)
            const u16* row = &X[(bL + idx) * NT1];
            kb = row + 512; vb = row + 1024;
            rp_ = &rpe[((size_t)qk + (c - 1)) * PE];
            const float d = distances[qk + c - 1];         // s_load (uniform)
            biasc = -(d * d) * inv2sig;
        } else {
            kb = &Kg[(size_t)(bG + c - 17) * INNER];
            vb = &Vg[(size_t)(bG + c - 17) * INNER];
            biasc = gbias;
        }
        ushort8_t kv = *reinterpret_cast<const ushort8_t*>(kb + lane * 8);
        ushort8_t vv = *reinterpret_cast<const ushort8_t*>(vb + lane * 8);
        float4 r4 = {0.f,0.f,0.f,0.f};
        if (c < 17) r4 = *reinterpret_cast<const float4*>(rp_ + r * 4);

        float part = bf2f(kv[0])*qf[0] + bf2f(kv[1])*qf[1]
                   + bf2f(kv[2])*qf[2] + bf2f(kv[3])*qf[3]
                   + bf2f(kv[4])*qf[4] + bf2f(kv[5])*qf[5]
                   + bf2f(kv[6])*qf[6] + bf2f(kv[7])*qf[7];
        if (c < 17)
            part += r4.x*t4[0] + r4.y*t4[1] + r4.z*t4[2] + r4.w*t4[3];
        part += __shfl_xor(part, 1);
        part += __shfl_xor(part, 2);
        part += __shfl_xor(part, 4);

        const float logit = part * SCALE + biasc;          // group-uniform
        const float mn = fmaxf(m, logit);
        const float f  = __expf(m - mn);
        const float e  = __expf(logit - mn);
        denom = denom * f + e;
        #pragma unroll
        for (int i = 0; i < 8; ++i) acc[i] = acc[i] * f + e * bf2f(vv[i]);
        if (c < 17) {
            rb[0] = rb[0] * f + e * r4.x;  rb[1] = rb[1] * f + e * r4.y;
            rb[2] = rb[2] * f + e * r4.z;  rb[3] = rb[3] * f + e * r4.w;
        } else {
            rb[0] *= f; rb[1] *= f; rb[2] *= f; rb[3] *= f;
        }
        m = mn;
    }

    const float inv = 1.f / denom;
    ushort4_t ru = { f2bf(rb[0]*inv), f2bf(rb[1]*inv), f2bf(rb[2]*inv), f2bf(rb[3]*inv) };
    *reinterpret_cast<ushort4_t*>(&ob2[(size_t)q * KT2 + 512 + h * 32 + r * 4]) = ru;
    ushort8_t ou = { f2bf(acc[0]*inv), f2bf(acc[1]*inv), f2bf(acc[2]*inv), f2bf(acc[3]*inv),
                     f2bf(acc[4]*inv), f2bf(acc[5]*inv), f2bf(acc[6]*inv), f2bf(acc[7]*inv) };
    *reinterpret_cast<ushort8_t*>(&ob2[(size_t)q * KT2 + lane * 8]) = ou;
}

// ---------------------------------------------------------------------------
extern "C" void kernel_launch(void* const* d_in, const int* in_sizes, int n_in,
                              void* d_out, int out_size, void* d_ws, size_t ws_size,
                              hipStream_t stream)
{
    const float* spatial     = (const float*)d_in[0];
    const int*   topk        = (const int*)  d_in[1];
    const float* rpe         = (const float*)d_in[2];
    const float* self_rpe    = (const float*)d_in[3];
    const float* distances   = (const float*)d_in[4];
    const float* gl          = (const float*)d_in[5];
    const float* Wq          = (const float*)d_in[6];
    const float* Wk          = (const float*)d_in[7];
    const float* Wv          = (const float*)d_in[8];
    const float* Wo          = (const float*)d_in[9];
    const float* bo          = (const float*)d_in[10];
    const float* log_sigma   = (const float*)d_in[11];
    const float* global_bias = (const float*)d_in[12];
    float* out = (float*)d_out;

    char* p = (char*)d_ws;
    float* A   = (float*)p;  p += (size_t)256 * 256 * 4;
    float* M2  = (float*)p;  p += (size_t)256 * 256 * 4;
    u16* Sb    = (u16*)p;    p += (size_t)MM * DD * 2;
    u16* Wt    = (u16*)p;    p += (size_t)NT1 * KT1 * 2;
    u16* Wot   = (u16*)p;    p += (size_t)NT2 * KT2 * 2;
    u16* X     = (u16*)p;    p += (size_t)MM * NT1 * 2;
    u16* ob2   = (u16*)p;    p += (size_t)MM * KT2 * 2;
    u16* Kg    = (u16*)p;    p += (size_t)BB * GG * INNER * 2;
    u16* Vg    = (u16*)p;    p += (size_t)BB * GG * INNER * 2;

    prep_A <<<256, 256, 0, stream>>>(Wq, Wk, A);
    prep_M2<<<256, 256, 0, stream>>>(Wv, Wo, M2);
    cast_spatial<<<MM * DD / (256 * 8), 256, 0, stream>>>(spatial, Sb);
    prep_wcat_t<<<dim3(NT1 / 64, KT1 / 64), 256, 0, stream>>>(Wq, Wk, Wv, A, Wt);
    prep_wout_t<<<dim3(NT2 / 64, KT2 / 64), 256, 0, stream>>>(Wo, M2, Wot);
    gemm_globals<<<dim3(BB * GG, 4), 256, 0, stream>>>(gl, Wk, Wv, Kg, Vg);

    mfma_gemm<KT1, 256, NT1, 128, false><<<dim3(MM / 128, NT1 / 128), 256, 0, stream>>>(
        Sb, Wt, X, nullptr, nullptr);

    attn_kernel<<<MM / 4, 256, 0, stream>>>(
        X, Kg, Vg, topk, rpe, self_rpe, distances, log_sigma, global_bias, ob2);

    mfma_gemm<KT2, KT2, NT2, 64, true><<<dim3(MM / 128, NT2 / 64), 256, 0, stream>>>(
        ob2, Wot, nullptr, out, bo);
}